// Round 15
// baseline (177.189 us; speedup 1.0000x reference)
//
#include <hip/hip_runtime.h>
#include <hip/hip_fp16.h>

#define OUTF 11008
#define INF  4096
#define NTILES 688
#define MAGICU 0x7E57C0DEu

typedef unsigned int uint;
typedef __attribute__((ext_vector_type(8))) _Float16 f16x8;  // MFMA A/B (4 VGPR)
typedef __attribute__((ext_vector_type(4))) float f32x4;     // MFMA C/D

typedef __attribute__((address_space(1))) void gvoid_t;
typedef __attribute__((address_space(3))) void svoid_t;

union UA { uint4 u4; uint u[4]; f16x8 v; };
union UH { uint u; __half2 h; };
union USH { unsigned short s; __half h; };

#define WAITV(n) asm volatile("s_waitcnt vmcnt(" #n ")" ::: "memory")
#define FENCE()  asm volatile("" ::: "memory")   // compiler-order pin

// Single dispatch. Blocks 0..31 additionally pack xpk (256 fragments each);
// all blocks overlap their weight/norm DMA + LUT build with the pack, then
// wave 0 spins on 32 exact-match flag words before A-fragment loads.
__global__ __launch_bounds__(256, 3) void lin2bit_fused(
    const float* __restrict__ x, uint4* __restrict__ xpk, uint* __restrict__ flags,
    const int* __restrict__ wq, const float* __restrict__ wn,
    const float* __restrict__ bias, float* __restrict__ out)
{
  __shared__ __align__(16) char lds[43008];
  char* LUT = lds;

  const int tid = threadIdx.x;
  const int wv  = tid >> 6;
  const int l   = tid & 63;
  const int col = l & 15;
  const int q   = l >> 4;
  const int bid = (int)blockIdx.x;
  const int o0  = bid << 4;

  char* NL = lds + 2048 + wv * 2048;
  char* W0 = lds + 10240 + wv * 8192;
  char* W1 = W0 + 4096;

  const char* wqb = (const char*)wq;
  const char* wnb = (const char*)wn;

  // ---- producer phase: blocks 0..31 pack xpk (fragment f = bid*256 + tid)
  if (bid < 32) {
    const int f = bid * 256 + tid;
    const int kblk = f >> 6, fl = f & 63, fcol = fl & 15, fq = fl >> 4;
    const float* src = x + (size_t)fcol * INF + kblk * 32 + fq * 8;
    const float4 a = *(const float4*)src;
    const float4 b = *(const float4*)(src + 4);
    UH c0, c1, c2, c3;
    c0.h = __floats2half2_rn(a.x, a.y);
    c1.h = __floats2half2_rn(a.z, a.w);
    c2.h = __floats2half2_rn(b.x, b.y);
    c3.h = __floats2half2_rn(b.z, b.w);
    xpk[f] = make_uint4(c0.u, c1.u, c2.u, c3.u);
    __syncthreads();                 // drains the pack stores (vmcnt 0 at barrier)
    if (tid == 0) {
      __threadfence();               // device-scope visibility of xpk
      __hip_atomic_store(&flags[bid], MAGICU, __ATOMIC_RELEASE,
                         __HIP_MEMORY_SCOPE_AGENT);
    }
  }

  // ---- everyone: issue norm + W0 + W1 DMAs (flag-independent prefetch)
  {
    const int r7 = l >> 3;
    const char* s0 = wnb + (size_t)(o0 + r7) * 512 + wv * 128 + (((l & 7) ^ r7) << 4);
#pragma unroll
    for (int i = 0; i < 2; ++i)
      __builtin_amdgcn_global_load_lds((gvoid_t*)(s0 + (size_t)i * 8 * 512),
                                       (svoid_t*)(NL + i * 1024 + l * 16), 16, 0, 0);
  }
  FENCE();

#define STAGE_W(c, buf) { \
    _Pragma("unroll") \
    for (int i = 0; i < 4; ++i) { \
      const int r = 4 * i + (l >> 4); \
      const char* src = wqb + (size_t)(o0 + r) * 4096 + wv * 1024 + (c) * 256 \
                        + (((l & 15) ^ (r & 7)) << 4); \
      __builtin_amdgcn_global_load_lds((gvoid_t*)src, \
                                       (svoid_t*)((buf) + i * 1024 + l * 16), 16, 0, 0); \
    } }

  STAGE_W(0, W0);  FENCE();
  STAGE_W(1, W1);  FENCE();

  // ---- LUT build on VALU while DMAs + pack fly
  {
    USH h0, h1, h2, h3;
    h0.h = __float2half(-1.0f);  h1.h = __float2half(-0.333f);
    h2.h = __float2half(0.333f); h3.h = __float2half(1.0f);
    const uint hv[4] = {h0.s, h1.s, h2.s, h3.s};
#pragma unroll
    for (int e = 0; e < 4; ++e) {
      const int idx = e * 64 + l;
      const uint lo = hv[idx & 3]        | (hv[(idx >> 2) & 3] << 16);
      const uint hi = hv[(idx >> 4) & 3] | (hv[(idx >> 6) & 3] << 16);
      *(uint2*)(LUT + idx * 8) = make_uint2(lo, hi);
    }
  }

  // ---- consumer gate: wave 0 spins until all 32 packer words == MAGIC
  if (tid < 64) {
    bool ok = false;
    while (!ok) {
      bool all = true;
#pragma unroll
      for (int i = 0; i < 32; ++i) {
        const uint v = __hip_atomic_load(&flags[i], __ATOMIC_ACQUIRE,
                                         __HIP_MEMORY_SCOPE_AGENT);
        all = all && (v == MAGICU);
      }
      ok = all;
      if (!ok) __builtin_amdgcn_s_sleep(16);
    }
  }
  __syncthreads();   // releases the block; also drains all outstanding VMEM

#define LOAD_AF(buf, c) { \
    _Pragma("unroll") \
    for (int j = 0; j < 8; ++j) \
      (buf)[j].u4 = xpk[(size_t)(wv * 32 + (c) * 8 + j) * 64 + l]; }

  UA afA[8], afB[8];
  LOAD_AF(afA, 0); FENCE();
  LOAD_AF(afB, 1); FENCE();    // outstanding: AF0(8) AF1(8) = 16

  f32x4 acc = {0.f, 0.f, 0.f, 0.f};
  const int cs7 = col & 7;
  const int qh  = q >> 1;
  const int ql8 = (q & 1) * 8;

#define CHUNK(wb, af, c) { \
    const float4 n0 = *(const float4*)(NL + col * 128 + (((2 * (c))     ^ cs7) << 4)); \
    const float4 n1 = *(const float4*)(NL + col * 128 + (((2 * (c) + 1) ^ cs7) << 4)); \
    __half2 nv2[8]; \
    nv2[0] = __floats2half2_rn(n0.x, n0.x); nv2[1] = __floats2half2_rn(n0.y, n0.y); \
    nv2[2] = __floats2half2_rn(n0.z, n0.z); nv2[3] = __floats2half2_rn(n0.w, n0.w); \
    nv2[4] = __floats2half2_rn(n1.x, n1.x); nv2[5] = __floats2half2_rn(n1.y, n1.y); \
    nv2[6] = __floats2half2_rn(n1.z, n1.z); nv2[7] = __floats2half2_rn(n1.w, n1.w); \
    _Pragma("unroll") \
    for (int j = 0; j < 8; ++j) { \
      const uint2 p  = *(const uint2*)((wb) + col * 256 + (((2 * j + qh) ^ cs7) << 4) + ql8); \
      const uint2 e0 = *(const uint2*)(LUT + ((size_t)(uint)p.x << 3)); \
      const uint2 e1 = *(const uint2*)(LUT + ((size_t)(uint)p.y << 3)); \
      UH a0, a1, a2, a3, b0, b1, b2, b3; \
      a0.u = e0.x; a1.u = e0.y; a2.u = e1.x; a3.u = e1.y; \
      b0.h = __hmul2(a0.h, nv2[j]); b1.h = __hmul2(a1.h, nv2[j]); \
      b2.h = __hmul2(a2.h, nv2[j]); b3.h = __hmul2(a3.h, nv2[j]); \
      UA B; B.u[0] = b0.u; B.u[1] = b1.u; B.u[2] = b2.u; B.u[3] = b3.u; \
      acc = __builtin_amdgcn_mfma_f32_16x16x32_f16((af)[j].v, B.v, acc, 0, 0, 0); \
    } }

  WAITV(8);  CHUNK(W0, afA, 0)     // AF0 retired (W0/W1 drained at barrier)
  FENCE();   STAGE_W(2, W0);  FENCE();  LOAD_AF(afA, 2);  FENCE();
  WAITV(12); CHUNK(W1, afB, 1)     // AF1 retired; W2+AF2 in flight
  FENCE();   STAGE_W(3, W1);  FENCE();  LOAD_AF(afB, 3);  FENCE();
  WAITV(12); CHUNK(W0, afA, 2)     // W2+AF2 retired; W3+AF3 in flight
  WAITV(0);  CHUNK(W1, afB, 3)
#undef CHUNK
#undef STAGE_W
#undef LOAD_AF

  // ---- cross-wave K reduction + bias + store
  __syncthreads();
  float* red = (float*)lds;
  red[wv * 256 +   0 + l] = acc[0];
  red[wv * 256 +  64 + l] = acc[1];
  red[wv * 256 + 128 + l] = acc[2];
  red[wv * 256 + 192 + l] = acc[3];
  __syncthreads();
  const int t = tid;
  const float s = red[t] + red[256 + t] + red[512 + t] + red[768 + t];
  const int m  = ((t & 63) >> 4) * 4 + (t >> 6);
  const int oc = t & 15;
  out[(size_t)m * OUTF + o0 + oc] = s + bias[o0 + oc];
}

extern "C" void kernel_launch(void* const* d_in, const int* in_sizes, int n_in,
                              void* d_out, int out_size, void* d_ws, size_t ws_size,
                              hipStream_t stream) {
  (void)in_sizes; (void)n_in; (void)out_size; (void)ws_size;
  const float* x    = (const float*)d_in[0];
  const int*   wq   = (const int*)d_in[1];
  const float* wn   = (const float*)d_in[2];
  const float* bias = (const float*)d_in[3];
  float*       out  = (float*)d_out;
  uint*        flags = (uint*)d_ws;                       // 32 words
  uint4*       xpk   = (uint4*)((char*)d_ws + 256);       // 128 KB fragments
  lin2bit_fused<<<dim3(NTILES), dim3(256), 0, stream>>>(x, xpk, flags, wq, wn, bias, out);
}

// Round 16
// 21.505 us; speedup vs baseline: 8.2393x; 8.2393x over previous
//
#include <hip/hip_runtime.h>
#include <hip/hip_fp16.h>

#define OUTF 11008
#define INF  4096
#define NTILES 688

typedef unsigned int uint;
typedef __attribute__((ext_vector_type(8))) _Float16 f16x8;  // MFMA A/B (4 VGPR)
typedef __attribute__((ext_vector_type(4))) float f32x4;     // MFMA C/D

typedef __attribute__((address_space(1))) void gvoid_t;
typedef __attribute__((address_space(3))) void svoid_t;

union UA { uint4 u4; uint u[4]; f16x8 v; };
union UH { uint u; __half2 h; };
union USH { unsigned short s; __half h; };

#define WAITV(n) asm volatile("s_waitcnt vmcnt(" #n ")" ::: "memory")
#define SBAR()   __builtin_amdgcn_sched_barrier(0)
#define FENCE()  asm volatile("" ::: "memory")   // compiler-order pin

// ---- pre-pack x (f32 16x4096) -> f16 MFMA A-fragments. 64 blocks x 128 thr.
__global__ __launch_bounds__(128) void pack_x_kernel(const float* __restrict__ x,
                                                     uint4* __restrict__ xpk) {
  const int t = (int)blockIdx.x * 128 + (int)threadIdx.x;   // 0..8191
  const int kblk = t >> 6, l = t & 63, col = l & 15, q = l >> 4;
  const float* src = x + (size_t)col * INF + kblk * 32 + q * 8;
  const float4 a = *(const float4*)src;
  const float4 b = *(const float4*)(src + 4);
  UH c0, c1, c2, c3;
  c0.h = __floats2half2_rn(a.x, a.y);
  c1.h = __floats2half2_rn(a.z, a.w);
  c2.h = __floats2half2_rn(b.x, b.y);
  c3.h = __floats2half2_rn(b.z, b.w);
  xpk[t] = make_uint4(c0.u, c1.u, c2.u, c3.u);
}

// R9 structure; A-fragment prefetch forced via volatile asm global_load_dwordx4
// (un-sinkable, guaranteed register-resident -> vmcnt ladder is real).
__global__ __launch_bounds__(256, 3) void lin2bit_kernel(
    const uint4* __restrict__ xpk, const int* __restrict__ wq,
    const float* __restrict__ wn, const float* __restrict__ bias,
    float* __restrict__ out)
{
  __shared__ __align__(16) char lds[43008];
  char* LUT = lds;

  const int tid = threadIdx.x;
  const int wv  = tid >> 6;
  const int l   = tid & 63;
  const int col = l & 15;
  const int q   = l >> 4;
  const int o0  = (int)blockIdx.x << 4;

  char* NL = lds + 2048 + wv * 2048;
  char* W0 = lds + 10240 + wv * 8192;
  char* W1 = W0 + 4096;

  const char* wqb = (const char*)wq;
  const char* wnb = (const char*)wn;

  // ---- norms DMA: 2 instr, 8 rows each, 16B/lane, source-side XOR swizzle
  {
    const int r7 = l >> 3;
    const char* s0 = wnb + (size_t)(o0 + r7) * 512 + wv * 128 + (((l & 7) ^ r7) << 4);
#pragma unroll
    for (int i = 0; i < 2; ++i)
      __builtin_amdgcn_global_load_lds((gvoid_t*)(s0 + (size_t)i * 8 * 512),
                                       (svoid_t*)(NL + i * 1024 + l * 16), 16, 0, 0);
  }
  FENCE();

#define STAGE_W(c, buf) { \
    _Pragma("unroll") \
    for (int i = 0; i < 4; ++i) { \
      const int r = 4 * i + (l >> 4); \
      const char* src = wqb + (size_t)(o0 + r) * 4096 + wv * 1024 + (c) * 256 \
                        + (((l & 15) ^ (r & 7)) << 4); \
      __builtin_amdgcn_global_load_lds((gvoid_t*)src, \
                                       (svoid_t*)((buf) + i * 1024 + l * 16), 16, 0, 0); \
    } }

  // A-fragment prefetch: volatile asm loads -> cannot be sunk by the compiler
#define LOAD_AF(buf, c) { \
    _Pragma("unroll") \
    for (int j = 0; j < 8; ++j) { \
      const uint4* p = xpk + (size_t)(wv * 32 + (c) * 8 + j) * 64 + l; \
      asm volatile("global_load_dwordx4 %0, %1, off" \
                   : "=&v"((buf)[j].u4) : "v"(p) : "memory"); \
    } }

  UA afA[8], afB[8];
  STAGE_W(0, W0);  FENCE();
  LOAD_AF(afA, 0); FENCE();
  STAGE_W(1, W1);  FENCE();
  LOAD_AF(afB, 1); FENCE();
  // vmcnt queue (oldest first): NR(2) W0(4) afA(8) W1(4) afB(8) = 26

  // ---- LUT build on VALU while 26 VMEM in flight
  {
    USH h0, h1, h2, h3;
    h0.h = __float2half(-1.0f);  h1.h = __float2half(-0.333f);
    h2.h = __float2half(0.333f); h3.h = __float2half(1.0f);
    const uint hv[4] = {h0.s, h1.s, h2.s, h3.s};
#pragma unroll
    for (int e = 0; e < 4; ++e) {
      const int idx = e * 64 + l;
      const uint lo = hv[idx & 3]        | (hv[(idx >> 2) & 3] << 16);
      const uint hi = hv[(idx >> 4) & 3] | (hv[(idx >> 6) & 3] << 16);
      *(uint2*)(LUT + idx * 8) = make_uint2(lo, hi);
    }
  }

  f32x4 acc = {0.f, 0.f, 0.f, 0.f};
  const int cs7 = col & 7;
  const int qh  = q >> 1;
  const int ql8 = (q & 1) * 8;

#define CHUNK(wb, af, c) { \
    const float4 n0 = *(const float4*)(NL + col * 128 + (((2 * (c))     ^ cs7) << 4)); \
    const float4 n1 = *(const float4*)(NL + col * 128 + (((2 * (c) + 1) ^ cs7) << 4)); \
    __half2 nv2[8]; \
    nv2[0] = __floats2half2_rn(n0.x, n0.x); nv2[1] = __floats2half2_rn(n0.y, n0.y); \
    nv2[2] = __floats2half2_rn(n0.z, n0.z); nv2[3] = __floats2half2_rn(n0.w, n0.w); \
    nv2[4] = __floats2half2_rn(n1.x, n1.x); nv2[5] = __floats2half2_rn(n1.y, n1.y); \
    nv2[6] = __floats2half2_rn(n1.z, n1.z); nv2[7] = __floats2half2_rn(n1.w, n1.w); \
    _Pragma("unroll") \
    for (int j = 0; j < 8; ++j) { \
      const uint2 p  = *(const uint2*)((wb) + col * 256 + (((2 * j + qh) ^ cs7) << 4) + ql8); \
      const uint2 e0 = *(const uint2*)(LUT + ((size_t)(uint)p.x << 3)); \
      const uint2 e1 = *(const uint2*)(LUT + ((size_t)(uint)p.y << 3)); \
      UH a0, a1, a2, a3, b0, b1, b2, b3; \
      a0.u = e0.x; a1.u = e0.y; a2.u = e1.x; a3.u = e1.y; \
      b0.h = __hmul2(a0.h, nv2[j]); b1.h = __hmul2(a1.h, nv2[j]); \
      b2.h = __hmul2(a2.h, nv2[j]); b3.h = __hmul2(a3.h, nv2[j]); \
      UA B; B.u[0] = b0.u; B.u[1] = b1.u; B.u[2] = b2.u; B.u[3] = b3.u; \
      acc = __builtin_amdgcn_mfma_f32_16x16x32_f16((af)[j].v, B.v, acc, 0, 0, 0); \
    } }

  // ladder: each wait retires exactly the streams the next chunk needs
  WAITV(12); SBAR(); CHUNK(W0, afA, 0)        // NR+W0+afA retired
  FENCE();   STAGE_W(2, W0);  FENCE();  LOAD_AF(afA, 2);  FENCE();
  WAITV(12); SBAR(); CHUNK(W1, afB, 1)        // W1+afB retired
  FENCE();   STAGE_W(3, W1);  FENCE();  LOAD_AF(afB, 3);  FENCE();
  WAITV(12); SBAR(); CHUNK(W0, afA, 2)        // W2+afA2 retired
  WAITV(0);  SBAR(); CHUNK(W1, afB, 3)        // all retired
#undef CHUNK
#undef STAGE_W
#undef LOAD_AF

  // ---- cross-wave K reduction + bias + store
  __syncthreads();
  float* red = (float*)lds;
  red[wv * 256 +   0 + l] = acc[0];
  red[wv * 256 +  64 + l] = acc[1];
  red[wv * 256 + 128 + l] = acc[2];
  red[wv * 256 + 192 + l] = acc[3];
  __syncthreads();
  const int t = tid;
  const float s = red[t] + red[256 + t] + red[512 + t] + red[768 + t];
  const int m  = ((t & 63) >> 4) * 4 + (t >> 6);
  const int oc = t & 15;
  out[(size_t)m * OUTF + o0 + oc] = s + bias[o0 + oc];
}

extern "C" void kernel_launch(void* const* d_in, const int* in_sizes, int n_in,
                              void* d_out, int out_size, void* d_ws, size_t ws_size,
                              hipStream_t stream) {
  (void)in_sizes; (void)n_in; (void)out_size; (void)ws_size;
  const float* x    = (const float*)d_in[0];
  const int*   wq   = (const int*)d_in[1];
  const float* wn   = (const float*)d_in[2];
  const float* bias = (const float*)d_in[3];
  float*       out  = (float*)d_out;
  uint4*       xpk  = (uint4*)d_ws;   // 128 KB workspace
  pack_x_kernel<<<dim3(64), dim3(128), 0, stream>>>(x, xpk);
  lin2bit_kernel<<<dim3(NTILES), dim3(256), 0, stream>>>(xpk, wq, wn, bias, out);
}

// Round 17
// 19.660 us; speedup vs baseline: 9.0125x; 1.0938x over previous
//
#include <hip/hip_runtime.h>
#include <hip/hip_fp16.h>

#define OUTF 11008
#define INF  4096
#define NTILES 688

typedef unsigned int uint;
typedef __attribute__((ext_vector_type(8))) _Float16 f16x8;  // MFMA A/B (4 VGPR)
typedef __attribute__((ext_vector_type(4))) float f32x4;     // MFMA C/D

typedef __attribute__((address_space(1))) void gvoid_t;
typedef __attribute__((address_space(3))) void svoid_t;

union UA { uint4 u4; uint u[4]; f16x8 v; };
union UH { uint u; __half2 h; };
union USH { unsigned short s; __half h; };

#define WAITV(n) asm volatile("s_waitcnt vmcnt(" #n ")" ::: "memory")
#define FENCE()  asm volatile("" ::: "memory")
#define BARRIER() { FENCE(); __builtin_amdgcn_s_barrier(); FENCE(); }

// Single kernel. Block = 256 thr = 4 waves, one 16-row o-tile, 16 block-global
// K-chunks of 256k. Waves split the 8 groups of each chunk (2 MFMA each).
// x is staged per-chunk f32 into shared LDS via coalesced global_load_lds
// (DMA per-lane src does the row transpose); fragments cvt f32->f16 in-reg.
__global__ __launch_bounds__(256, 3) void lin2bit_kernel(
    const float* __restrict__ x, const int* __restrict__ wq,
    const float* __restrict__ wn, const float* __restrict__ bias,
    float* __restrict__ out)
{
  // [0,2048) LUT | [2048,10240) norms | [10240,43008) X0/X1 16KB | [43008,51200) W0/W1 4KB
  __shared__ __align__(16) char lds[51200];
  char* LUT = lds;
  char* NL  = lds + 2048;
  char* X0  = lds + 10240;
  char* X1  = lds + 26624;
  char* W0  = lds + 43008;
  char* W1  = lds + 47104;

  const int tid = threadIdx.x;
  const int wv  = tid >> 6;
  const int l   = tid & 63;
  const int col = l & 15;            // A-row (m) / B-col (o)
  const int q   = l >> 4;            // lane covers k = 8q..8q+7 of each group
  const int o0  = (int)blockIdx.x << 4;

  const char* xb  = (const char*)x;
  const char* wqb = (const char*)wq;
  const char* wnb = (const char*)wn;

  // ---- norms DMA once: 8 KB, 8 instr (2/wave); 16B-granule swizzle key r&7
  {
#pragma unroll
    for (int ii = 0; ii < 2; ++ii) {
      const int i = wv * 2 + ii;
      const int r = 2 * i + (l >> 5);
      const char* src = wnb + (size_t)(o0 + r) * 512 + (((l & 31) ^ (r & 7)) << 4);
      __builtin_amdgcn_global_load_lds((gvoid_t*)src,
                                       (svoid_t*)(NL + i * 1024 + l * 16), 16, 0, 0);
    }
  }
  FENCE();

  // chunk x-slab: [row][1024B], 32B-granule swizzle key r&7; 4 instr/wave (row i each)
#define STAGE_X(c, buf) { \
    _Pragma("unroll") \
    for (int ii = 0; ii < 4; ++ii) { \
      const int i = wv * 4 + ii; \
      const char* src = xb + (size_t)i * 16384 + (size_t)(c) * 1024 \
                        + ((((l >> 1) ^ (i & 7)) << 5) | ((l & 1) << 4)); \
      __builtin_amdgcn_global_load_lds((gvoid_t*)src, \
                                       (svoid_t*)((buf) + i * 1024 + l * 16), 16, 0, 0); \
    } }

  // chunk W-slab: [row][256B], 16B-granule swizzle key r&7; 1 instr/wave (4 rows)
#define STAGE_W(c, buf) { \
    const int r = wv * 4 + (l >> 4); \
    const char* src = wqb + (size_t)(o0 + r) * 4096 + (size_t)(c) * 256 \
                      + (((l & 15) ^ (r & 7)) << 4); \
    __builtin_amdgcn_global_load_lds((gvoid_t*)src, \
                                     (svoid_t*)((buf) + wv * 1024 + l * 16), 16, 0, 0); }

  STAGE_X(0, X0); STAGE_W(0, W0); FENCE();
  STAGE_X(1, X1); STAGE_W(1, W1); FENCE();
  // per-wave outstanding: norms(2) + S0(5) + S1(5) = 12

  // ---- LUT build on VALU while DMAs fly (same-wave ordering compiler-handled)
  {
    USH h0, h1, h2, h3;
    h0.h = __float2half(-1.0f);  h1.h = __float2half(-0.333f);
    h2.h = __float2half(0.333f); h3.h = __float2half(1.0f);
    const uint hv[4] = {h0.s, h1.s, h2.s, h3.s};
#pragma unroll
    for (int e = 0; e < 4; ++e) {
      const int idx = e * 64 + l;
      const uint lo = hv[idx & 3]        | (hv[(idx >> 2) & 3] << 16);
      const uint hi = hv[(idx >> 4) & 3] | (hv[(idx >> 6) & 3] << 16);
      *(uint2*)(LUT + idx * 8) = make_uint2(lo, hi);
    }
  }

  f32x4 acc = {0.f, 0.f, 0.f, 0.f};
  const int c7 = col & 7;

#define COMPUTE(c, xs, ws) { \
    const int naddr = col * 512 + ((((c) * 2 + (wv >> 1)) ^ c7) << 4) + (wv & 1) * 8; \
    const float2 nn = *(const float2*)(NL + naddr); \
    _Pragma("unroll") \
    for (int jj = 0; jj < 2; ++jj) { \
      const int g = wv * 2 + jj; \
      const float nv = jj ? nn.y : nn.x; \
      UH nvh; nvh.h = __floats2half2_rn(nv, nv); \
      const uint2 p = *(const uint2*)((ws) + col * 256 \
                        + (((g * 2 + (q >> 1)) ^ c7) << 4) + (q & 1) * 8); \
      const int xaddr = col * 1024 + (((g * 4 + q) ^ c7) << 5); \
      const float4 xa = *(const float4*)((xs) + xaddr); \
      const float4 xc = *(const float4*)((xs) + xaddr + 16); \
      UH k0, k1, k2, k3; \
      k0.h = __floats2half2_rn(xa.x, xa.y); k1.h = __floats2half2_rn(xa.z, xa.w); \
      k2.h = __floats2half2_rn(xc.x, xc.y); k3.h = __floats2half2_rn(xc.z, xc.w); \
      UA A; A.u[0] = k0.u; A.u[1] = k1.u; A.u[2] = k2.u; A.u[3] = k3.u; \
      const uint2 e0 = *(const uint2*)(LUT + ((size_t)(uint)p.x << 3)); \
      const uint2 e1 = *(const uint2*)(LUT + ((size_t)(uint)p.y << 3)); \
      UH a0, a1, a2, a3, b0, b1, b2, b3; \
      a0.u = e0.x; a1.u = e0.y; a2.u = e1.x; a3.u = e1.y; \
      b0.h = __hmul2(a0.h, nvh.h); b1.h = __hmul2(a1.h, nvh.h); \
      b2.h = __hmul2(a2.h, nvh.h); b3.h = __hmul2(a3.h, nvh.h); \
      UA B; B.u[0] = b0.u; B.u[1] = b1.u; B.u[2] = b2.u; B.u[3] = b3.u; \
      acc = __builtin_amdgcn_mfma_f32_16x16x32_f16(A.v, B.v, acc, 0, 0, 0); \
    } }

  // iters 0..13: wait own 5 -> barrier (slab c ready block-wide) -> compute ->
  // barrier (slab c free block-wide) -> stage c+2 into it
#define ITER_FULL(c, XS, WS) \
  WAITV(5); BARRIER(); \
  COMPUTE(c, XS, WS) \
  BARRIER(); \
  STAGE_X((c) + 2, XS); STAGE_W((c) + 2, WS); FENCE();

  ITER_FULL(0,  X0, W0)  ITER_FULL(1,  X1, W1)
  ITER_FULL(2,  X0, W0)  ITER_FULL(3,  X1, W1)
  ITER_FULL(4,  X0, W0)  ITER_FULL(5,  X1, W1)
  ITER_FULL(6,  X0, W0)  ITER_FULL(7,  X1, W1)
  ITER_FULL(8,  X0, W0)  ITER_FULL(9,  X1, W1)
  ITER_FULL(10, X0, W0)  ITER_FULL(11, X1, W1)
  ITER_FULL(12, X0, W0)  ITER_FULL(13, X1, W1)
  WAITV(5); BARRIER(); COMPUTE(14, X0, W0)
  WAITV(0); BARRIER(); COMPUTE(15, X1, W1)
#undef ITER_FULL
#undef COMPUTE
#undef STAGE_X
#undef STAGE_W

  // ---- cross-wave K reduction (overlay on LUT+norms after barrier) + store
  __syncthreads();
  float* red = (float*)lds;
  red[wv * 256 +   0 + l] = acc[0];
  red[wv * 256 +  64 + l] = acc[1];
  red[wv * 256 + 128 + l] = acc[2];
  red[wv * 256 + 192 + l] = acc[3];
  __syncthreads();
  const int t = tid;
  const float s = red[t] + red[256 + t] + red[512 + t] + red[768 + t];
  const int m  = ((t & 63) >> 4) * 4 + (t >> 6);   // D row = q*4 + reg
  const int oc = t & 15;                            // D col
  out[(size_t)m * OUTF + o0 + oc] = s + bias[o0 + oc];
}

extern "C" void kernel_launch(void* const* d_in, const int* in_sizes, int n_in,
                              void* d_out, int out_size, void* d_ws, size_t ws_size,
                              hipStream_t stream) {
  (void)in_sizes; (void)n_in; (void)out_size; (void)d_ws; (void)ws_size;
  const float* x    = (const float*)d_in[0];
  const int*   wq   = (const int*)d_in[1];
  const float* wn   = (const float*)d_in[2];
  const float* bias = (const float*)d_in[3];
  float*       out  = (float*)d_out;
  lin2bit_kernel<<<dim3(NTILES), dim3(256), 0, stream>>>(x, wq, wn, bias, out);
}